// Round 9
// baseline (7797.362 us; speedup 1.0000x reference)
//
#include <hip/hip_runtime.h>
#include <hip/hip_bf16.h>

// PBRNN LSTM: B=64, S=512, D=544, H=1024. out = [h_n; c_n] fp32 [2,64,1024].
//
// Round 9: R6 structure (best: 2342us) + progressive rotated consumption.
//  - Tagged-word self-timed h exchange via LIC, 256 blocks = 64 cg x 4 bg,
//    W in VGPRs, XCD swizzle, poll issued at top of step (R8 taught us:
//    issuing the poll right after the store is ALWAYS stale + adds LIC
//    contention at publication time -- reverted).
//  - NEW: per-fragment validate->extract->MFMA in an order rotated per
//    consumer (rot = cg&7): early producers' slabs are consumed while
//    stragglers publish; the max-of-64 skew is paid once, overlapped with
//    7/8 of the hh MFMA work, instead of gating all of it.
//  - v_perm extract kept from R8 (not implicated in the regression).

#define B_  64
#define S_  512
#define D_  544
#define H_  1024
#define CG_ 64
#define BG_ 4
#define GRID_ (CG_*BG_)

typedef __attribute__((ext_vector_type(8))) short bf16x8;
typedef __attribute__((ext_vector_type(4))) float f32x4;

__device__ inline ushort f2b(float x){
  unsigned u = __float_as_uint(x);
  u = (u + 0x7FFFu + ((u >> 16) & 1u)) >> 16;   // RNE
  return (ushort)u;
}

__device__ inline bf16x8 pack8(float4 a, float4 b){
  bf16x8 r;
  r[0]=(short)f2b(a.x); r[1]=(short)f2b(a.y); r[2]=(short)f2b(a.z); r[3]=(short)f2b(a.w);
  r[4]=(short)f2b(b.x); r[5]=(short)f2b(b.y); r[6]=(short)f2b(b.z); r[7]=(short)f2b(b.w);
  return r;
}

__device__ inline unsigned long long ld64a(const unsigned long long* q){
  return __hip_atomic_load(q, __ATOMIC_RELAXED, __HIP_MEMORY_SCOPE_AGENT);
}

__device__ inline float sigm(float x){ return __builtin_amdgcn_rcpf(1.f + __expf(-x)); }
__device__ inline float tanh_(float x){ return 1.f - 2.f*__builtin_amdgcn_rcpf(1.f + __expf(2.f*x)); }

__global__ void cvt_x(const float* __restrict__ x, ushort* __restrict__ xb, int n4){
  int i = blockIdx.x*256 + threadIdx.x;
  if (i >= n4) return;
  float4 v = ((const float4*)x)[i];
  ushort4 o;
  o.x=f2b(v.x); o.y=f2b(v.y); o.z=f2b(v.z); o.w=f2b(v.w);
  ((ushort4*)xb)[i] = o;
}

__global__ __launch_bounds__(256,1) void lstm_persist(
    const float* __restrict__ Wih, const float* __restrict__ Whh,
    const float* __restrict__ bih, const float* __restrict__ bhh,
    const ushort* __restrict__ Xb,
    unsigned* thbuf,       // [2][BG_][CG_][16 n][16 k] tagged words, pre-zeroed
    float* __restrict__ out)
{
  const int tid  = threadIdx.x;
  const int wave = tid >> 6;          // K-quarter for W_hh
  const int lane = tid & 63;
  const int c16  = lane & 15;
  const int quad = lane >> 4;
  // XCD-affinity swizzle: XCD = blockIdx%8 (round-robin dispatch)
  const int bg   = (blockIdx.x & 7) >> 1;
  const int cg   = ((blockIdx.x >> 3) << 1) | (blockIdx.x & 1);
  const int rot  = cg & 7;            // progressive-consumption rotation

  // double-buffered per-wave gate partials
  __shared__ float gates_s[2][4][64][17];

  // ---- W_hh A-fragments (VGPR-pinned): 4 M-tiles (gates i,f,g,o) x 8 K-iters
  bf16x8 whhf[4][8];
  #pragma unroll
  for (int mt = 0; mt < 4; ++mt){
    const size_t grow = (size_t)(mt*H_ + cg*16 + c16);
    #pragma unroll
    for (int i = 0; i < 8; ++i){
      int k = wave*256 + i*32 + quad*8;
      const float4* p = (const float4*)(Whh + grow*H_ + k);
      whhf[mt][i] = pack8(p[0], p[1]);
    }
  }
  // ---- W_ih A-fragments: K-iters it = wave, wave+4, ... < 17 ----
  bf16x8 wihf[4][5];
  #pragma unroll
  for (int mt = 0; mt < 4; ++mt){
    const size_t grow = (size_t)(mt*H_ + cg*16 + c16);
    #pragma unroll
    for (int ii = 0; ii < 5; ++ii){
      int it = wave + 4*ii;
      if (it < 17){
        int k = it*32 + quad*8;
        const float4* p = (const float4*)(Wih + grow*D_ + k);
        wihf[mt][ii] = pack8(p[0], p[1]);
      }
    }
  }

  // ---- update mapping: thread owns (batch nn, col uu) ----
  const int uu = tid & 15;
  const int nn = tid >> 4;
  float bsum[4];
  #pragma unroll
  for (int g = 0; g < 4; ++g)
    bsum[g] = bih[g*H_ + cg*16 + uu] + bhh[g*H_ + cg*16 + uu];
  float cstate = 0.f;

  f32x4 acc[4];      // [gate tile]
  bf16x8 xraw[5];    // raw X fragments for the NEXT xp_gemm (preloaded)

  auto zacc = [&]{
    #pragma unroll
    for (int mt = 0; mt < 4; ++mt) acc[mt] = (f32x4){0.f,0.f,0.f,0.f};
  };
  auto ldx = [&](int t){            // issue raw X loads (no compute dep)
    if (t >= S_) t = S_-1;          // clamp: avoid OOB on the tail prefetch
    #pragma unroll
    for (int ii = 0; ii < 5; ++ii){
      int it = wave + 4*ii;
      if (it < 17)
        xraw[ii] = *(const bf16x8*)(Xb + ((size_t)(bg*16 + c16)*S_ + t)*D_ + it*32 + quad*8);
    }
  };
  auto xp_mfma = [&]{               // consume xraw (loads long since landed)
    #pragma unroll
    for (int ii = 0; ii < 5; ++ii){
      int it = wave + 4*ii;
      if (it < 17){
        #pragma unroll
        for (int mt = 0; mt < 4; ++mt)
          acc[mt] = __builtin_amdgcn_mfma_f32_16x16x32_bf16(wihf[mt][ii], xraw[ii], acc[mt], 0,0,0);
      }
    }
  };

  // prologue: xp(0) computed, X(1) in flight
  ldx(0);
  zacc();
  xp_mfma();
  ldx(1);

  // consumer fragment word offset (excluding the i*512 term):
  // slab = bg*64 + wave*16 + i*2 + (quad>>1); word = slab*256 + c16*16 + (quad&1)*8
  const int obase = (bg*64 + wave*16 + (quad>>1))*256 + c16*16 + (quad&1)*8;

  for (int t = 0; t < S_; ++t){
    const unsigned* hp = thbuf + (t & 1) * (B_*H_);
    unsigned*       hn = thbuf + ((t & 1) ^ 1) * (B_*H_);

    const unsigned tag = (unsigned)t & 0xffffu;
    const unsigned long long tmask = 0xffff0000ffff0000ull;
    const unsigned long long texp  = ((unsigned long long)tag << 16)
                                   | ((unsigned long long)tag << 48);

    // ---- 1. issue all 32 poll loads up-front (MLP across fragments) ----
    unsigned long long q[8][4];
    #pragma unroll
    for (int i = 0; i < 8; ++i){
      const unsigned long long* p = (const unsigned long long*)(hp + obase + i*512);
      q[i][0] = ld64a(p);   q[i][1] = ld64a(p+1);
      q[i][2] = ld64a(p+2); q[i][3] = ld64a(p+3);
    }

    // ---- 2. progressive rotated consume: validate frag -> extract -> MFMA
    #pragma unroll
    for (int ii = 0; ii < 8; ++ii){
      const int i = (ii + rot) & 7;
      const unsigned long long* p = (const unsigned long long*)(hp + obase + i*512);
      long rounds = 0;
      while ((((q[i][0]^texp)|(q[i][1]^texp)|(q[i][2]^texp)|(q[i][3]^texp)) & tmask) != 0ull){
        q[i][0] = ld64a(p);   q[i][1] = ld64a(p+1);
        q[i][2] = ld64a(p+2); q[i][3] = ld64a(p+3);
        if (++rounds > (1L<<20)) break;   // safety: never hang the harness
      }
      union { unsigned u[4]; bf16x8 v8; } eb;
      #pragma unroll
      for (int w = 0; w < 4; ++w){
        unsigned lo = (unsigned)q[i][w];
        unsigned hi = (unsigned)(q[i][w] >> 32);
        eb.u[w] = __builtin_amdgcn_perm(hi, lo, 0x05040100u);
      }
      #pragma unroll
      for (int mt = 0; mt < 4; ++mt)
        acc[mt] = __builtin_amdgcn_mfma_f32_16x16x32_bf16(whhf[mt][i], eb.v8, acc[mt], 0,0,0);
    }

    // ---- 3. per-wave partials -> LDS (ping-pong, 1 barrier/step) ----
    #pragma unroll
    for (int mt = 0; mt < 4; ++mt)
      #pragma unroll
      for (int r = 0; r < 4; ++r)
        gates_s[t & 1][wave][mt*16 + quad*4 + r][c16] = acc[mt][r];
    __syncthreads();

    // ---- 4. nonlinearity + state update + tagged h store ----
    {
      float gsum[4];
      #pragma unroll
      for (int g = 0; g < 4; ++g){
        float s = bsum[g];
        #pragma unroll
        for (int q2 = 0; q2 < 4; ++q2) s += gates_s[t & 1][q2][g*16 + uu][nn];
        gsum[g] = s;
      }
      float iv = sigm(gsum[0]), fv = sigm(gsum[1]), gv = tanh_(gsum[2]), ov = sigm(gsum[3]);
      float cn = fv*cstate + iv*gv;
      cstate = cn;
      float hv = ov*tanh_(cn);
      unsigned word = (((unsigned)(t+1) & 0xffffu) << 16) | (unsigned)f2b(hv);
      __hip_atomic_store(hn + (size_t)(bg*64 + cg)*256 + tid, word,
                         __ATOMIC_RELAXED, __HIP_MEMORY_SCOPE_AGENT);
      if (t == S_-1){
        out[(bg*16 + nn)*H_ + cg*16 + uu]          = hv;   // h_n
        out[B_*H_ + (bg*16 + nn)*H_ + cg*16 + uu]  = cn;   // c_n
      }
    }

    // ---- 5. xp(t+1) from preloaded xraw; issue X(t+2) loads ----
    if (t < S_-1){
      zacc();
      xp_mfma();     // X(t+1), already resident
      ldx(t + 2);    // in flight across poll(t+1)
    }
  }
}

extern "C" void kernel_launch(void* const* d_in, const int* in_sizes, int n_in,
                              void* d_out, int out_size, void* d_ws, size_t ws_size,
                              hipStream_t stream) {
  const float* X   = (const float*)d_in[0];
  const float* Wih = (const float*)d_in[1];
  const float* Whh = (const float*)d_in[2];
  const float* bih = (const float*)d_in[3];
  const float* bhh = (const float*)d_in[4];
  float* out = (float*)d_out;

  // ws layout: [0, 512KB) tagged h double buffer, [512KB, +35.7MB) X bf16.
  char* ws = (char*)d_ws;
  const size_t THBUF_BYTES = 2ull * B_ * H_ * sizeof(unsigned);     // 524288
  const size_t XB_OFF      = THBUF_BYTES;
  const size_t XB_BYTES    = (size_t)B_ * S_ * D_ * sizeof(ushort); // 35.65 MB
  if (ws_size < XB_OFF + XB_BYTES) return;  // insufficient scratch: fail visibly

  unsigned* thbuf = (unsigned*)ws;
  ushort*   Xb    = (ushort*)(ws + XB_OFF);

  hipMemsetAsync(d_ws, 0, THBUF_BYTES, stream);   // tags=0, h0=0

  int n4 = B_*S_*D_/4;
  cvt_x<<<(n4 + 255)/256, 256, 0, stream>>>(X, Xb, n4);
  lstm_persist<<<GRID_, 256, 0, stream>>>(Wih, Whh, bih, bhh, Xb, thbuf, out);
}